// Round 4
// baseline (174.148 us; speedup 1.0000x reference)
//
#include <hip/hip_runtime.h>

typedef __bf16 bf16_t;
typedef __attribute__((ext_vector_type(8))) __bf16 bf16x8;
typedef __attribute__((ext_vector_type(8))) unsigned short u16x8;
typedef __attribute__((ext_vector_type(4))) float f32x4;

#define MFMA(a, b, c) __builtin_amdgcn_mfma_f32_16x16x32_bf16((a), (b), (c), 0, 0, 0)

__device__ __forceinline__ float bf2f(unsigned short s) {
    unsigned u = ((unsigned)s) << 16;
    return __builtin_bit_cast(float, u);
}
__device__ __forceinline__ unsigned short f2bf(float f) {
    return __builtin_bit_cast(unsigned short, (bf16_t)f);
}

// ---------------------------------------------------------------------------
// ws layout (unsigned short elements):
//   W1s: [0,16384)         W1s[cc*4096 + n*32 + kk] = W1[(cc*32+kk)*128 + n]
//   W2s: [16384,32768)     same for W2
//   W3s: [32768,34816)     W3s[o*128 + k] = W3[k*12+o] (o<12, else 0)
//   W0s: [34816,120832)    W0s[cc*4096 + n*32 + kk] = W0[f(k')][n],
//                          k'=cc*32+kk, f=(k'&7)*81+(k'>>3), 0 if k'>=648
//   inp_bf: [120832,522240) channel-last bf16: inp_bf[p*8+c] = inp[c*50176+p]
// ---------------------------------------------------------------------------
__global__ void inr_prep(const float* __restrict__ inp,
                         const float* __restrict__ W0,
                         const float* __restrict__ W1,
                         const float* __restrict__ W2,
                         const float* __restrict__ W3,
                         unsigned short* __restrict__ wsb)
{
    for (int idx = blockIdx.x * 256 + threadIdx.x; idx < 171008; idx += 334 * 256) {
        if (idx < 16384) {
            int cc = idx >> 12, rem = idx & 4095, n = rem >> 5, kk = rem & 31;
            wsb[idx] = f2bf(W1[(cc * 32 + kk) * 128 + n]);
        } else if (idx < 32768) {
            int j = idx - 16384;
            int cc = j >> 12, rem = j & 4095, n = rem >> 5, kk = rem & 31;
            wsb[idx] = f2bf(W2[(cc * 32 + kk) * 128 + n]);
        } else if (idx < 34816) {
            int r = idx - 32768;
            int o = r >> 7, k = r & 127;
            wsb[idx] = f2bf((o < 12) ? W3[k * 12 + o] : 0.f);
        } else if (idx < 120832) {
            int j = idx - 34816;
            int cc = j >> 12, rem = j & 4095, n = rem >> 5, kk = rem & 31;
            int kp = cc * 32 + kk;
            float val = 0.f;
            if (kp < 648) {
                int tt = kp >> 3, c = kp & 7;
                val = W0[(c * 81 + tt) * 128 + n];
            }
            wsb[idx] = f2bf(val);
        } else {
            int p = idx - 120832;               // point 0..50175
            const float* src = inp + p;
            bf16x8 v;
            #pragma unroll
            for (int c = 0; c < 8; ++c) v[c] = (bf16_t)src[c * 50176];
            *(bf16x8*)&wsb[120832 + p * 8] = v;
        }
    }
}

// ---------------------------------------------------------------------------
// main fused kernel: 392 blocks x 512 threads; 128 points per block.
// Wave grid 4x2: wave (wm,wn) computes rows wm*32..+31, cols wn*64..+63.
// M=128/block halves the per-block weight-panel re-read volume vs M=64.
// ---------------------------------------------------------------------------
__global__ __launch_bounds__(512, 4)
void inr_main(const float* __restrict__ W0g,
              const float* __restrict__ b0g,
              const float* __restrict__ b1g,
              const float* __restrict__ b2g,
              const float* __restrict__ b3g,
              const bf16_t* __restrict__ wsb,
              float* __restrict__ out)
{
    __shared__ unsigned short h0buf[128][136];  // h0_base (pre-relu, +b0), bf16
    __shared__ unsigned short h1buf[128][136];  // h1 then h2, bf16
    __shared__ float ct4[4][128];               // per-iteration cell vectors

    const int tid  = threadIdx.x;
    const int lane = tid & 63;
    const int wave = tid >> 6;    // 0..7
    const int l15  = lane & 15;
    const int q    = lane >> 4;
    const int wm   = wave >> 1;   // m-quarter (0..3)
    const int wn   = wave & 1;    // n-half (0/1)
    // XCD-locality swizzle: 392 = 8 * 49
    const int tile = (blockIdx.x & 7) * 49 + (blockIdx.x >> 3);

    // ---- one-time staging: ct4 (read after the post-h0 barrier) ----
    if (tid < 128) {
        int k = tid;
        float wa = W0g[716 * 128 + k] + W0g[717 * 128 + k];
        float wb = W0g[718 * 128 + k] + W0g[719 * 128 + k];
        float p = 32.f;
        #pragma unroll
        for (int it = 0; it < 4; ++it) { ct4[it][k] = p * wa + wb; p *= 32.f; }
    }

    // ---- per-lane constants ----
    float b0v[4], b1v[4], b2v[4];
    #pragma unroll
    for (int nb = 0; nb < 4; ++nb) {
        int col = wn * 64 + nb * 16 + l15;
        b0v[nb] = b0g[col]; b1v[nb] = b1g[col]; b2v[nb] = b2g[col];
    }

    // ---- point decode for the register A-gather (2 rows per lane) ----
    int u0[2], v0[2], i0[2], j0[2];
    float gln[2];
    #pragma unroll
    for (int mb = 0; mb < 2; ++mb) {
        int n_g = tile * 128 + wm * 32 + mb * 16 + l15;
        int Bi = n_g >> 10, ppt = n_g & 1023;
        u0[mb] = Bi / 7; v0[mb] = Bi - 7 * u0[mb];
        i0[mb] = ppt >> 5; j0[mb] = ppt & 31;
        gln[mb] = (ppt < 2) ? 0.0625f : ((ppt < 4) ? (2.f / 7.f) : 1.f);
    }

    const bf16x8* W0s8 = (const bf16x8*)&wsb[34816];
    const bf16x8* W1s8 = (const bf16x8*)&wsb[0];
    const bf16x8* W2s8 = (const bf16x8*)&wsb[16384];
    const bf16x8* W3s8 = (const bf16x8*)&wsb[32768];
    const bf16x8* inpb8 = (const bf16x8*)&wsb[120832];  // [plane_point][8ch]

    // ================= layer 0: barrier-free K-loop =================
    f32x4 acc0[2][4];
    #pragma unroll
    for (int mb = 0; mb < 2; ++mb)
        #pragma unroll
        for (int nb = 0; nb < 4; ++nb)
            acc0[mb][nb] = (f32x4){0.f, 0.f, 0.f, 0.f};

    for (int cc = 0; cc < 21; ++cc) {
        // W0 frags direct from global (L2-resident bf16 panel)
        bf16x8 wf[4];
        #pragma unroll
        for (int nb = 0; nb < 4; ++nb)
            wf[nb] = W0s8[cc * 512 + (wn * 64 + nb * 16 + l15) * 4 + q];

        // tap decode (per q)
        int t = cc * 4 + q;
        int s = t / 9, a = t - 9 * s;
        int ki = s / 3, kj = s - 3 * ki, ku = a / 3, kv = a - 3 * ku;
        bool tap_ok = (t < 81);

        #pragma unroll
        for (int mb = 0; mb < 2; ++mb) {
            int uu = u0[mb] + ku - 1, vv = v0[mb] + kv - 1;
            int ii = i0[mb] + ki - 1, jj = j0[mb] + kj - 1;
            bf16x8 af;
            #pragma unroll
            for (int e = 0; e < 8; ++e) af[e] = (bf16_t)0.f;
            if (tap_ok && (unsigned)uu < 7u && (unsigned)vv < 7u &&
                (unsigned)ii < 32u && (unsigned)jj < 32u) {
                af = inpb8[((uu * 7 + vv) << 10) + (ii << 5) + jj];  // 16B, 8 ch
            }
            #pragma unroll
            for (int nb = 0; nb < 4; ++nb)
                acc0[mb][nb] = MFMA(af, wf[nb], acc0[mb][nb]);
        }
    }

    // h0_base = acc0 + b0 -> bf16 LDS
    #pragma unroll
    for (int mb = 0; mb < 2; ++mb)
        #pragma unroll
        for (int nb = 0; nb < 4; ++nb) {
            int col = wn * 64 + nb * 16 + l15;
            #pragma unroll
            for (int r = 0; r < 4; ++r)
                h0buf[wm * 32 + mb * 16 + q * 4 + r][col] = f2bf(acc0[mb][nb][r] + b0v[nb]);
        }

    // hoist W3 fragments (reused every iteration)
    bf16x8 wf3[4];
    #pragma unroll
    for (int cc = 0; cc < 4; ++cc) wf3[cc] = W3s8[l15 * 16 + cc * 4 + q];

    __syncthreads();

    // ================= 4 iterations of the 3 remaining layers =================
    f32x4 outacc = (f32x4){0.f, 0.f, 0.f, 0.f};

    for (int it = 0; it < 4; ++it) {
        // ---- layer 1: A = relu(h0 + g*ct_it) built on the fly ----
        f32x4 acc1[2][4];
        #pragma unroll
        for (int mb = 0; mb < 2; ++mb)
            #pragma unroll
            for (int nb = 0; nb < 4; ++nb) acc1[mb][nb] = (f32x4){0.f, 0.f, 0.f, 0.f};

        #pragma unroll
        for (int cc = 0; cc < 4; ++cc) {
            int k0 = cc * 32 + q * 8;
            f32x4 ct0 = *(const f32x4*)&ct4[it][k0];
            f32x4 ct1 = *(const f32x4*)&ct4[it][k0 + 4];
            bf16x8 wf[4];
            #pragma unroll
            for (int nb = 0; nb < 4; ++nb)
                wf[nb] = W1s8[cc * 512 + (wn * 64 + nb * 16 + l15) * 4 + q];
            #pragma unroll
            for (int mb = 0; mb < 2; ++mb) {
                u16x8 hv = *(const u16x8*)&h0buf[wm * 32 + mb * 16 + l15][k0];
                float g = gln[mb];
                bf16x8 af;
                #pragma unroll
                for (int e = 0; e < 8; ++e) {
                    float ctv = (e < 4) ? ct0[e] : ct1[e - 4];
                    float x = bf2f(hv[e]) + g * ctv;
                    af[e] = (bf16_t)fmaxf(x, 0.f);
                }
                #pragma unroll
                for (int nb = 0; nb < 4; ++nb)
                    acc1[mb][nb] = MFMA(af, wf[nb], acc1[mb][nb]);
            }
        }
        // h1 = relu(acc1 + b1) -> h1buf
        #pragma unroll
        for (int mb = 0; mb < 2; ++mb)
            #pragma unroll
            for (int nb = 0; nb < 4; ++nb) {
                int col = wn * 64 + nb * 16 + l15;
                #pragma unroll
                for (int r = 0; r < 4; ++r)
                    h1buf[wm * 32 + mb * 16 + q * 4 + r][col] =
                        f2bf(fmaxf(acc1[mb][nb][r] + b1v[nb], 0.f));
            }
        __syncthreads();

        // ---- layer 2 ----
        f32x4 acc2[2][4];
        #pragma unroll
        for (int mb = 0; mb < 2; ++mb)
            #pragma unroll
            for (int nb = 0; nb < 4; ++nb) acc2[mb][nb] = (f32x4){0.f, 0.f, 0.f, 0.f};

        #pragma unroll
        for (int cc = 0; cc < 4; ++cc) {
            int k0 = cc * 32 + q * 8;
            bf16x8 wf[4];
            #pragma unroll
            for (int nb = 0; nb < 4; ++nb)
                wf[nb] = W2s8[cc * 512 + (wn * 64 + nb * 16 + l15) * 4 + q];
            #pragma unroll
            for (int mb = 0; mb < 2; ++mb) {
                bf16x8 af = *(const bf16x8*)&h1buf[wm * 32 + mb * 16 + l15][k0];
                #pragma unroll
                for (int nb = 0; nb < 4; ++nb)
                    acc2[mb][nb] = MFMA(af, wf[nb], acc2[mb][nb]);
            }
        }
        __syncthreads();  // all h1 reads done before overwrite

        // h2 = relu(acc2 + b2) -> h1buf (reuse)
        #pragma unroll
        for (int mb = 0; mb < 2; ++mb)
            #pragma unroll
            for (int nb = 0; nb < 4; ++nb) {
                int col = wn * 64 + nb * 16 + l15;
                #pragma unroll
                for (int r = 0; r < 4; ++r)
                    h1buf[wm * 32 + mb * 16 + q * 4 + r][col] =
                        f2bf(fmaxf(acc2[mb][nb][r] + b2v[nb], 0.f));
            }
        __syncthreads();

        // ---- layer 3: wave m-split (16 rows each), hoisted W3 frags ----
        #pragma unroll
        for (int cc = 0; cc < 4; ++cc) {
            int k0 = cc * 32 + q * 8;
            bf16x8 af = *(const bf16x8*)&h1buf[wave * 16 + l15][k0];
            outacc = MFMA(af, wf3[cc], outacc);  // accumulates across cc AND it
        }
        __syncthreads();  // protect h1buf for next iteration's L1 write
    }

    // ======== epilogue: LDS transpose -> fully-coalesced float4 stores ========
    {
        float* sf = (float*)h0buf;           // 128 x 13 floats (6656 B)
        if (l15 < 12) {
            float b3v = b3g[l15];
            #pragma unroll
            for (int r = 0; r < 4; ++r)
                sf[(wave * 16 + q * 4 + r) * 13 + l15] = 0.25f * outacc[r] + b3v;
        }
        __syncthreads();
        if (tid < 384) {
            int ch = tid >> 7;                 // 0..2
            int idx = tid & 127;
            int il = idx >> 5, s = (idx >> 4) & 1, cg = idx & 15;
            int ng0 = tile << 7;
            int B2 = ng0 >> 10, pq0 = ng0 & 1023;
            int u2 = B2 / 7, v2 = B2 - 7 * u2;
            int i0b = pq0 >> 5;                // multiple of 4
            f32x4 v;
            #pragma unroll
            for (int e = 0; e < 4; ++e) {
                int col = cg * 4 + e;
                int j = col >> 1, t2 = col & 1;
                v[e] = sf[(il * 32 + j) * 13 + ch * 4 + s * 2 + t2];
            }
            int row = 2 * (i0b + il) + s;
            *(f32x4*)&out[((ch * 7 + u2) * 7 + v2) * 4096 + row * 64 + cg * 4] = v;
        }
    }
}

extern "C" void kernel_launch(void* const* d_in, const int* in_sizes, int n_in,
                              void* d_out, int out_size, void* d_ws, size_t ws_size,
                              hipStream_t stream)
{
    (void)in_sizes; (void)n_in; (void)out_size; (void)ws_size;
    const float* inp = (const float*)d_in[0];
    const float* W0  = (const float*)d_in[1];
    const float* b0  = (const float*)d_in[2];
    const float* W1  = (const float*)d_in[3];
    const float* b1  = (const float*)d_in[4];
    const float* W2  = (const float*)d_in[5];
    const float* b2  = (const float*)d_in[6];
    const float* W3  = (const float*)d_in[7];
    const float* b3  = (const float*)d_in[8];
    float* out = (float*)d_out;
    unsigned short* wsb = (unsigned short*)d_ws;

    inr_prep<<<334, 256, 0, stream>>>(inp, W0, W1, W2, W3, wsb);
    inr_main<<<392, 512, 0, stream>>>(W0, b0, b1, b2, b3, (const bf16_t*)wsb, out);
}

// Round 5
// 122.253 us; speedup vs baseline: 1.4245x; 1.4245x over previous
//
#include <hip/hip_runtime.h>

typedef __bf16 bf16_t;
typedef __attribute__((ext_vector_type(8))) __bf16 bf16x8;
typedef __attribute__((ext_vector_type(8))) unsigned short u16x8;
typedef __attribute__((ext_vector_type(4))) float f32x4;

#define MFMA(a, b, c) __builtin_amdgcn_mfma_f32_16x16x32_bf16((a), (b), (c), 0, 0, 0)

__device__ __forceinline__ float bf2f(unsigned short s) {
    unsigned u = ((unsigned)s) << 16;
    return __builtin_bit_cast(float, u);
}
__device__ __forceinline__ unsigned short f2bf(float f) {
    return __builtin_bit_cast(unsigned short, (bf16_t)f);
}

// ---------------------------------------------------------------------------
// ws layout (unsigned short elements):
//   W1s: [0,16384)         W1s[cc*4096 + n*32 + kk] = W1[(cc*32+kk)*128 + n]
//   W2s: [16384,32768)     same for W2
//   W3s: [32768,34816)     W3s[o*128 + k] = W3[k*12+o] (o<12, else 0)
//   W0s: [34816,120832)    W0s[cc*4096 + n*32 + kk] = W0[f(k')][n],
//                          k'=cc*32+kk, f=(k'&7)*81+(k'>>3), 0 if k'>=648
//   inp_bf: [120832,522240) channel-last bf16: inp_bf[p*8+c] = inp[c*50176+p]
// ---------------------------------------------------------------------------
__global__ void inr_prep(const float* __restrict__ inp,
                         const float* __restrict__ W0,
                         const float* __restrict__ W1,
                         const float* __restrict__ W2,
                         const float* __restrict__ W3,
                         unsigned short* __restrict__ wsb)
{
    for (int idx = blockIdx.x * 256 + threadIdx.x; idx < 171008; idx += 334 * 256) {
        if (idx < 16384) {
            int cc = idx >> 12, rem = idx & 4095, n = rem >> 5, kk = rem & 31;
            wsb[idx] = f2bf(W1[(cc * 32 + kk) * 128 + n]);
        } else if (idx < 32768) {
            int j = idx - 16384;
            int cc = j >> 12, rem = j & 4095, n = rem >> 5, kk = rem & 31;
            wsb[idx] = f2bf(W2[(cc * 32 + kk) * 128 + n]);
        } else if (idx < 34816) {
            int r = idx - 32768;
            int o = r >> 7, k = r & 127;
            wsb[idx] = f2bf((o < 12) ? W3[k * 12 + o] : 0.f);
        } else if (idx < 120832) {
            int j = idx - 34816;
            int cc = j >> 12, rem = j & 4095, n = rem >> 5, kk = rem & 31;
            int kp = cc * 32 + kk;
            float val = 0.f;
            if (kp < 648) {
                int tt = kp >> 3, c = kp & 7;
                val = W0[(c * 81 + tt) * 128 + n];
            }
            wsb[idx] = f2bf(val);
        } else {
            int p = idx - 120832;               // point 0..50175
            const float* src = inp + p;
            bf16x8 v;
            #pragma unroll
            for (int c = 0; c < 8; ++c) v[c] = (bf16_t)src[c * 50176];
            *(bf16x8*)&wsb[120832 + p * 8] = v;
        }
    }
}

// ---------------------------------------------------------------------------
// main fused kernel: 784 blocks x 256 threads; 64 points per block.
// Wave grid 2x2. Latency-exposure fixes:
//  - input gather staged once into an LDS slab (9 views x 4 rows x 36 cols)
//  - layer-0 W0 frags double-buffer-prefetched from global
//  - W1/W2/W3 fragments hoisted into registers for the whole MLP phase
// ---------------------------------------------------------------------------
__global__ __launch_bounds__(256, 2)
void inr_main(const float* __restrict__ W0g,
              const float* __restrict__ b0g,
              const float* __restrict__ b1g,
              const float* __restrict__ b2g,
              const float* __restrict__ b3g,
              const bf16_t* __restrict__ wsb,
              float* __restrict__ out)
{
    __shared__ unsigned short h0buf[64][136];  // h0_base (pre-relu, +b0), bf16
    __shared__ unsigned short h1buf[64][136];  // h1 then h2, bf16
    __shared__ float ct4[4][128];              // per-iteration cell vectors
    __shared__ bf16x8 slab[1300];              // gather slab; [1296]=zero

    const int tid  = threadIdx.x;
    const int lane = tid & 63;
    const int wave = tid >> 6;
    const int l15  = lane & 15;
    const int q    = lane >> 4;
    const int wm   = wave >> 1;   // m-half (0/1)
    const int wn   = wave & 1;    // n-half (0/1)
    const int tile = blockIdx.x;

    // block-uniform point decode: all 64 points share (u0,v0), i in {i0b, i0b+1}
    const int Bi = tile >> 4;
    const int u0 = Bi / 7, v0 = Bi - 7 * u0;
    const int i0b = (tile & 15) * 2;

    const bf16x8* W0s8 = (const bf16x8*)&wsb[34816];
    const bf16x8* W1s8 = (const bf16x8*)&wsb[0];
    const bf16x8* W2s8 = (const bf16x8*)&wsb[16384];
    const bf16x8* W3s8 = (const bf16x8*)&wsb[32768];
    const bf16x8* inpb8 = (const bf16x8*)&wsb[120832];  // [plane_point][8ch]

    // ---- one-time staging: ct4 (read only after the post-h0 barrier) ----
    if (tid < 128) {
        int k = tid;
        float wa = W0g[716 * 128 + k] + W0g[717 * 128 + k];
        float wb = W0g[718 * 128 + k] + W0g[719 * 128 + k];
        float p = 32.f;
        #pragma unroll
        for (int it = 0; it < 4; ++it) { ct4[it][k] = p * wa + wb; p *= 32.f; }
    }

    // ---- slab fill: 9 views x 4 rows x 36 cols, zero-padded OOB ----
    for (int s = tid; s < 1300; s += 256) {
        bf16x8 v;
        #pragma unroll
        for (int e = 0; e < 8; ++e) v[e] = (bf16_t)0.f;
        if (s < 1296) {
            int vd = s / 144, rem = s - vd * 144;
            int ri = rem / 36, jc = rem - ri * 36;
            int uu = u0 + vd / 3 - 1, vv = v0 + (vd - (vd / 3) * 3) - 1;
            int ii = i0b - 1 + ri, jj = jc - 1;
            if ((unsigned)uu < 7u && (unsigned)vv < 7u &&
                (unsigned)ii < 32u && (unsigned)jj < 32u)
                v = inpb8[((uu * 7 + vv) << 10) + (ii << 5) + jj];
        }
        slab[s] = v;
    }

    // ---- per-lane constants ----
    float b0v[4], b1v[4], b2v[4];
    #pragma unroll
    for (int nb = 0; nb < 4; ++nb) {
        int col = wn * 64 + nb * 16 + l15;
        b0v[nb] = b0g[col]; b1v[nb] = b1g[col]; b2v[nb] = b2g[col];
    }
    float gln[2];
    #pragma unroll
    for (int mb = 0; mb < 2; ++mb) {
        int ppt = (tile & 15) * 64 + wm * 32 + mb * 16 + l15;
        gln[mb] = (ppt < 2) ? 0.0625f : ((ppt < 4) ? (2.f / 7.f) : 1.f);
    }

    int nidx4[4];
    #pragma unroll
    for (int nb = 0; nb < 4; ++nb) nidx4[nb] = (wn * 64 + nb * 16 + l15) * 4 + q;

    __syncthreads();   // slab ready

    // A-frag slab index for chunk cc, m-block mb (t>=81 -> zero slot 1296)
    auto slab_idx = [&](int cc, int mb) -> int {
        int t = cc * 4 + q;
        if (t >= 81) return 1296;
        int s = t / 9, a = t - 9 * s;
        int ki = s / 3, kj = s - 3 * ki;
        return a * 144 + (wm + ki) * 36 + (mb * 16 + l15 + kj);
    };

    // ================= layer 0: prefetched, barrier-free K-loop =============
    f32x4 acc0[2][4];
    #pragma unroll
    for (int mb = 0; mb < 2; ++mb)
        #pragma unroll
        for (int nb = 0; nb < 4; ++nb)
            acc0[mb][nb] = (f32x4){0.f, 0.f, 0.f, 0.f};

    bf16x8 wfc[4], wfn[4], afc[2], afn[2];
    #pragma unroll
    for (int nb = 0; nb < 4; ++nb) wfc[nb] = W0s8[nidx4[nb]];
    afc[0] = slab[slab_idx(0, 0)];
    afc[1] = slab[slab_idx(0, 1)];

    for (int cc = 0; cc < 21; ++cc) {
        int nc = cc + 1;
        if (nc < 21) {
            #pragma unroll
            for (int nb = 0; nb < 4; ++nb) wfn[nb] = W0s8[nc * 512 + nidx4[nb]];
            afn[0] = slab[slab_idx(nc, 0)];
            afn[1] = slab[slab_idx(nc, 1)];
        }
        #pragma unroll
        for (int mb = 0; mb < 2; ++mb)
            #pragma unroll
            for (int nb = 0; nb < 4; ++nb)
                acc0[mb][nb] = MFMA(afc[mb], wfc[nb], acc0[mb][nb]);
        #pragma unroll
        for (int nb = 0; nb < 4; ++nb) wfc[nb] = wfn[nb];
        afc[0] = afn[0]; afc[1] = afn[1];
    }

    // h0_base = acc0 + b0 -> bf16 LDS
    #pragma unroll
    for (int mb = 0; mb < 2; ++mb)
        #pragma unroll
        for (int nb = 0; nb < 4; ++nb) {
            int col = wn * 64 + nb * 16 + l15;
            #pragma unroll
            for (int r = 0; r < 4; ++r)
                h0buf[wm * 32 + mb * 16 + q * 4 + r][col] = f2bf(acc0[mb][nb][r] + b0v[nb]);
        }

    // ---- hoist ALL MLP weight fragments into registers (once per block) ----
    bf16x8 w1r[4][4], w2r[4][4], wf3[4];
    #pragma unroll
    for (int cc = 0; cc < 4; ++cc)
        #pragma unroll
        for (int nb = 0; nb < 4; ++nb) {
            w1r[cc][nb] = W1s8[cc * 512 + nidx4[nb]];
            w2r[cc][nb] = W2s8[cc * 512 + nidx4[nb]];
        }
    #pragma unroll
    for (int cc = 0; cc < 4; ++cc) wf3[cc] = W3s8[l15 * 16 + cc * 4 + q];

    __syncthreads();

    // ================= 4 iterations of the 3 remaining layers ===============
    f32x4 outacc = (f32x4){0.f, 0.f, 0.f, 0.f};

    for (int it = 0; it < 4; ++it) {
        // ---- layer 1: A = relu(h0 + g*ct_it) built on the fly ----
        f32x4 acc1[2][4];
        #pragma unroll
        for (int mb = 0; mb < 2; ++mb)
            #pragma unroll
            for (int nb = 0; nb < 4; ++nb) acc1[mb][nb] = (f32x4){0.f, 0.f, 0.f, 0.f};

        #pragma unroll
        for (int cc = 0; cc < 4; ++cc) {
            int k0 = cc * 32 + q * 8;
            f32x4 ct0 = *(const f32x4*)&ct4[it][k0];
            f32x4 ct1 = *(const f32x4*)&ct4[it][k0 + 4];
            #pragma unroll
            for (int mb = 0; mb < 2; ++mb) {
                u16x8 hv = *(const u16x8*)&h0buf[wm * 32 + mb * 16 + l15][k0];
                float g = gln[mb];
                bf16x8 af;
                #pragma unroll
                for (int e = 0; e < 8; ++e) {
                    float ctv = (e < 4) ? ct0[e] : ct1[e - 4];
                    float x = bf2f(hv[e]) + g * ctv;
                    af[e] = (bf16_t)fmaxf(x, 0.f);
                }
                #pragma unroll
                for (int nb = 0; nb < 4; ++nb)
                    acc1[mb][nb] = MFMA(af, w1r[cc][nb], acc1[mb][nb]);
            }
        }
        // h1 = relu(acc1 + b1) -> h1buf
        #pragma unroll
        for (int mb = 0; mb < 2; ++mb)
            #pragma unroll
            for (int nb = 0; nb < 4; ++nb) {
                int col = wn * 64 + nb * 16 + l15;
                #pragma unroll
                for (int r = 0; r < 4; ++r)
                    h1buf[wm * 32 + mb * 16 + q * 4 + r][col] =
                        f2bf(fmaxf(acc1[mb][nb][r] + b1v[nb], 0.f));
            }
        __syncthreads();

        // ---- layer 2 (weights from registers) ----
        f32x4 acc2[2][4];
        #pragma unroll
        for (int mb = 0; mb < 2; ++mb)
            #pragma unroll
            for (int nb = 0; nb < 4; ++nb) acc2[mb][nb] = (f32x4){0.f, 0.f, 0.f, 0.f};

        #pragma unroll
        for (int cc = 0; cc < 4; ++cc) {
            int k0 = cc * 32 + q * 8;
            #pragma unroll
            for (int mb = 0; mb < 2; ++mb) {
                bf16x8 af = *(const bf16x8*)&h1buf[wm * 32 + mb * 16 + l15][k0];
                #pragma unroll
                for (int nb = 0; nb < 4; ++nb)
                    acc2[mb][nb] = MFMA(af, w2r[cc][nb], acc2[mb][nb]);
            }
        }
        __syncthreads();  // all h1 reads done before overwrite

        // h2 = relu(acc2 + b2) -> h1buf (reuse)
        #pragma unroll
        for (int mb = 0; mb < 2; ++mb)
            #pragma unroll
            for (int nb = 0; nb < 4; ++nb) {
                int col = wn * 64 + nb * 16 + l15;
                #pragma unroll
                for (int r = 0; r < 4; ++r)
                    h1buf[wm * 32 + mb * 16 + q * 4 + r][col] =
                        f2bf(fmaxf(acc2[mb][nb][r] + b2v[nb], 0.f));
            }
        __syncthreads();

        // ---- layer 3: wave m-split (16 rows each), register W3 frags ----
        #pragma unroll
        for (int cc = 0; cc < 4; ++cc) {
            int k0 = cc * 32 + q * 8;
            bf16x8 af = *(const bf16x8*)&h1buf[wave * 16 + l15][k0];
            outacc = MFMA(af, wf3[cc], outacc);  // accumulates across cc AND it
        }
        __syncthreads();  // protect h1buf for next iteration's L1 write
    }

    // ======== epilogue: LDS transpose -> fully-coalesced float4 stores ======
    {
        float* sf = (float*)h0buf;           // 64 x 13 floats
        if (l15 < 12) {
            float b3v = b3g[l15];
            #pragma unroll
            for (int r = 0; r < 4; ++r)
                sf[(wave * 16 + q * 4 + r) * 13 + l15] = 0.25f * outacc[r] + b3v;
        }
        __syncthreads();
        if (tid < 192) {
            int ch = tid >> 6, rr = (tid >> 4) & 3, cg = tid & 15;
            int il = rr >> 1, s = rr & 1;
            f32x4 v;
            #pragma unroll
            for (int e = 0; e < 4; ++e) {
                int col = cg * 4 + e;
                int j = col >> 1, t2 = col & 1;
                v[e] = sf[(il * 32 + j) * 13 + ch * 4 + s * 2 + t2];
            }
            int row = 2 * (i0b + il) + s;
            *(f32x4*)&out[((ch * 7 + u0) * 7 + v0) * 4096 + row * 64 + cg * 4] = v;
        }
    }
}

extern "C" void kernel_launch(void* const* d_in, const int* in_sizes, int n_in,
                              void* d_out, int out_size, void* d_ws, size_t ws_size,
                              hipStream_t stream)
{
    (void)in_sizes; (void)n_in; (void)out_size; (void)ws_size;
    const float* inp = (const float*)d_in[0];
    const float* W0  = (const float*)d_in[1];
    const float* b0  = (const float*)d_in[2];
    const float* W1  = (const float*)d_in[3];
    const float* b1  = (const float*)d_in[4];
    const float* W2  = (const float*)d_in[5];
    const float* b2  = (const float*)d_in[6];
    const float* W3  = (const float*)d_in[7];
    const float* b3  = (const float*)d_in[8];
    float* out = (float*)d_out;
    unsigned short* wsb = (unsigned short*)d_ws;

    inr_prep<<<334, 256, 0, stream>>>(inp, W0, W1, W2, W3, wsb);
    inr_main<<<784, 256, 0, stream>>>(W0, b0, b1, b2, b3, (const bf16_t*)wsb, out);
}